// Round 8
// baseline (1559.750 us; speedup 1.0000x reference)
//
#include <hip/hip_runtime.h>
#include <hip/hip_bf16.h>

#define Bsz 64
#define Tsz 512
#define Isz 512
#define Hsz 512

// ---------------- Phase 1: xU = x @ U + bias ----------------
__global__ __launch_bounds__(256) void p1_gemm(const float* __restrict__ X,
                                               const float* __restrict__ U,
                                               const float* __restrict__ bias,
                                               float* __restrict__ out) {
  const int K = Isz, N = Hsz;
  __shared__ float As[32][128];
  __shared__ float Bs[32][64];
  const int MB = (Bsz * Tsz) / 128;
  int bm = blockIdx.x & (MB - 1);
  int bn = blockIdx.x >> 8;
  int t = threadIdx.x;
  int tx = t & 15, ty = t >> 4;

  float acc[8][4];
#pragma unroll
  for (int r = 0; r < 8; r++)
#pragma unroll
    for (int c = 0; c < 4; c++) acc[r][c] = 0.f;

  const float* Xb = X + (size_t)bm * 128 * K;
  const float* Ub = U + bn * 64;

  for (int k0 = 0; k0 < K; k0 += 32) {
    int ar = t >> 3, aq = t & 7;
#pragma unroll
    for (int i = 0; i < 4; i++) {
      int row = ar + 32 * i;
      float4 v = *(const float4*)&Xb[(size_t)row * K + k0 + 4 * aq];
      As[4 * aq + 0][row] = v.x;
      As[4 * aq + 1][row] = v.y;
      As[4 * aq + 2][row] = v.z;
      As[4 * aq + 3][row] = v.w;
    }
    int bkk = t >> 4, bq = t & 15;
#pragma unroll
    for (int i = 0; i < 2; i++) {
      int kk = bkk + 16 * i;
      *(float4*)&Bs[kk][4 * bq] = *(const float4*)&Ub[(size_t)(k0 + kk) * N + 4 * bq];
    }
    __syncthreads();
#pragma unroll
    for (int kk = 0; kk < 32; kk++) {
      float4 A0 = *(const float4*)&As[kk][ty * 8];
      float4 A1 = *(const float4*)&As[kk][ty * 8 + 4];
      float4 B0 = *(const float4*)&Bs[kk][tx * 4];
      float av[8] = {A0.x, A0.y, A0.z, A0.w, A1.x, A1.y, A1.z, A1.w};
      float bv[4] = {B0.x, B0.y, B0.z, B0.w};
#pragma unroll
      for (int r = 0; r < 8; r++)
#pragma unroll
        for (int c = 0; c < 4; c++) acc[r][c] += av[r] * bv[c];
    }
    __syncthreads();
  }

  float4 bias4 = *(const float4*)&bias[bn * 64 + tx * 4];
  float bb[4] = {bias4.x, bias4.y, bias4.z, bias4.w};
#pragma unroll
  for (int r = 0; r < 8; r++) {
    float4 o;
    o.x = acc[r][0] + bb[0];
    o.y = acc[r][1] + bb[1];
    o.z = acc[r][2] + bb[2];
    o.w = acc[r][3] + bb[3];
    *(float4*)&out[((size_t)bm * 128 + ty * 8 + r) * N + bn * 64 + tx * 4] = o;
  }
}

// ---------------- Phase 2: recurrence — two batch-PIPELINES per block -------
// 32 groups x 8 blocks; group g owns batches {2g,2g+1} run as two independent
// pipelines A,B at a half-step offset, so each tagged-atom store gets a full
// compute+poll phase (~1000-1500 cyc) of propagation time before any block
// polls it -> sync latency hidden behind the other pipe's FMAs.
//   iter s: [compute A_s; store atomA tag s+1] [poll B tag s -> hB; barrier]
//           [compute B_s; store atomB tag s+1] [poll A tag s+1 -> hA; barrier]
// V: staged->LDS (r5 layout) then hoisted to 64 pinned scalar regs (r7).
// h: per-pipe double-buffered LDS, slot kp*64 + 2ks + e for k=16ks+2kp+e
//    -> float2 read at [kp*64 + 2ks] is 2-way (free); write is 1 b32.
// Reduce over 32 ks-lanes: 4 DPP + ds_swizzle xor16 (lanes 0..7 valid, r5/r7
// proven; owners are ks<4). Tag-in-atom protocol unchanged (no fences; 0xAA
// poison never matches). 256 blocks @ 1/CU co-resident -> no deadlock.
#define NGrp 32
#define BPGrp 8
#define CPB 64

__device__ __forceinline__ float ftanh(float x) {
  float ax = fabsf(x);
  float e = __expf(2.f * ax);
  float r = 1.f - 2.f / (e + 1.f);
  return copysignf(r, x);
}

template <int CTRL>
__device__ __forceinline__ float dppadd(float x) {
  int y = __builtin_amdgcn_update_dpp(0, __float_as_int(x), CTRL, 0xf, 0xf, true);
  return x + __int_as_float(y);
}
__device__ __forceinline__ float swz16add(float x) {  // += lane^16 (within 32)
  return x + __int_as_float(
                 __builtin_amdgcn_ds_swizzle(__float_as_int(x), 0x401F));
}

__device__ __forceinline__ unsigned long long packha(float h, int tag) {
  return (unsigned long long)__float_as_uint(h) |
         ((unsigned long long)(unsigned)tag << 32);
}

__device__ __forceinline__ float poll_one(unsigned long long* q, int want) {
  int guard = 0;
  while (true) {
    unsigned long long a =
        __hip_atomic_load(q, __ATOMIC_RELAXED, __HIP_MEMORY_SCOPE_AGENT);
    if ((int)(a >> 32) == want || ++guard > (1 << 20))
      return __uint_as_float((unsigned)a);  // guard: fail loud, not silent
  }
}

__global__ __launch_bounds__(512, 2) void p2_rnn(
    const float* __restrict__ h0, const float* __restrict__ V,
    float* __restrict__ out, unsigned long long* __restrict__ atoms) {
  extern __shared__ float sm[];  // V: 32768 | hA[2][512] | hB[2][512]
  float4* __restrict__ Vl = (float4*)sm;
  float* __restrict__ hA = sm + 32768;
  float* __restrict__ hB = sm + 32768 + 1024;

  int bid = blockIdx.x;
  int g = bid & 31;   // members share bid%32 -> same bid%8 -> same XCD-ish
  int jb = bid >> 5;  // column-block 0..7
  int t = threadIdx.x;
  int cq = t >> 5, ks = t & 31;

  // ---- stage V: coalesced float4 global reads, conflict-free LDS writes ----
  for (int rep = 0; rep < 16; rep++) {
    int idx = rep * 512 + t;
    int k = idx >> 4, cg = idx & 15;
    float4 gv = *(const float4*)&V[(size_t)k * Hsz + CPB * jb + 4 * cg];
    Vl[k * 16 + (cg ^ ((k >> 4) & 15))] = gv;
  }
  // ---- initial h state 0 for both pipes, slot kp*64 + 2ks + e ----
  const int islot = ((t & 15) >> 1) * 64 + 2 * (t >> 4) + (t & 1);
  hA[islot] = h0[(size_t)(2 * g + 0) * Hsz + t];
  hB[islot] = h0[(size_t)(2 * g + 1) * Hsz + t];
  __syncthreads();

  // ---- hoist this thread's V slice into 64 named scalar registers, PIN ----
  const int cs = cq ^ (ks & 15);
  const float4* vp = &Vl[(ks << 8) + cs];
#define LOADV(i)                                                     \
  float4 tv##i = vp[(i) * 16];                                       \
  float v##i##x = tv##i.x, v##i##y = tv##i.y, v##i##z = tv##i.z,     \
        v##i##w = tv##i.w;
  LOADV(0) LOADV(1) LOADV(2) LOADV(3) LOADV(4) LOADV(5) LOADV(6) LOADV(7)
  LOADV(8) LOADV(9) LOADV(10) LOADV(11) LOADV(12) LOADV(13) LOADV(14) LOADV(15)
#undef LOADV
  asm volatile("" : "+v"(v0x), "+v"(v0y), "+v"(v0z), "+v"(v0w),
                    "+v"(v1x), "+v"(v1y), "+v"(v1z), "+v"(v1w),
                    "+v"(v2x), "+v"(v2y), "+v"(v2z), "+v"(v2w),
                    "+v"(v3x), "+v"(v3y), "+v"(v3z), "+v"(v3w));
  asm volatile("" : "+v"(v4x), "+v"(v4y), "+v"(v4z), "+v"(v4w),
                    "+v"(v5x), "+v"(v5y), "+v"(v5z), "+v"(v5w),
                    "+v"(v6x), "+v"(v6y), "+v"(v6z), "+v"(v6w),
                    "+v"(v7x), "+v"(v7y), "+v"(v7z), "+v"(v7w));
  asm volatile("" : "+v"(v8x), "+v"(v8y), "+v"(v8z), "+v"(v8w),
                    "+v"(v9x), "+v"(v9y), "+v"(v9z), "+v"(v9w),
                    "+v"(v10x), "+v"(v10y), "+v"(v10z), "+v"(v10w),
                    "+v"(v11x), "+v"(v11y), "+v"(v11z), "+v"(v11w));
  asm volatile("" : "+v"(v12x), "+v"(v12y), "+v"(v12z), "+v"(v12w),
                    "+v"(v13x), "+v"(v13y), "+v"(v13z), "+v"(v13w),
                    "+v"(v14x), "+v"(v14y), "+v"(v14z), "+v"(v14w),
                    "+v"(v15x), "+v"(v15y), "+v"(v15z), "+v"(v15w));

  const bool own = (ks < 4);
  const int jj = ks & 3;
  const int col = CPB * jb + cq * 4 + jj;
  const size_t obA = ((size_t)(2 * g + 0) * Tsz) * Hsz + col;
  const size_t obB = ((size_t)(2 * g + 1) * Tsz) * Hsz + col;
  float xuA = own ? out[obA] : 0.f;
  float xuB = own ? out[obB] : 0.f;

  const int hb2 = 2 * ks;  // float2 read offset within an h state
  const int pk = t;        // polled element

// per-kp FMA for one pipe: h2 = (h[k0], h[k0+1]), V pairs (v2kp, v2kp+1)
#define PK2(H, kp, a, b, A0, A1, A2, A3)              \
  {                                                   \
    float2 h2 = *(const float2*)&(H)[(kp) * 64];      \
    A0 += v##a##x * h2.x + v##b##x * h2.y;            \
    A1 += v##a##y * h2.x + v##b##y * h2.y;            \
    A2 += v##a##z * h2.x + v##b##z * h2.y;            \
    A3 += v##a##w * h2.x + v##b##w * h2.y;            \
  }
#define PIPE_FMA(H, A0, A1, A2, A3)                                        \
  PK2(H, 0, 0, 1, A0, A1, A2, A3) PK2(H, 1, 2, 3, A0, A1, A2, A3)          \
  PK2(H, 2, 4, 5, A0, A1, A2, A3) PK2(H, 3, 6, 7, A0, A1, A2, A3)          \
  PK2(H, 4, 8, 9, A0, A1, A2, A3) PK2(H, 5, 10, 11, A0, A1, A2, A3)        \
  PK2(H, 6, 12, 13, A0, A1, A2, A3) PK2(H, 7, 14, 15, A0, A1, A2, A3)
#define RED(x)                 \
  x = dppadd<0xB1>(x);         \
  x = dppadd<0x4E>(x);         \
  x = dppadd<0x124>(x);        \
  x = dppadd<0x128>(x);        \
  x = swz16add(x);

  for (int s = 0; s < Tsz; s++) {
    const int par = s & 1, pn = (s + 1) & 1;

    // ======== phase 1: pipe A step s ========
    float xan = (own && s + 1 < Tsz) ? out[obA + (size_t)(s + 1) * Hsz] : 0.f;
    {
      const float* hp = &hA[par * 512 + hb2];
      float a0 = 0.f, a1 = 0.f, a2 = 0.f, a3 = 0.f;
      PIPE_FMA(hp, a0, a1, a2, a3)
      RED(a0) RED(a1) RED(a2) RED(a3)
      if (own) {
        float sum = (jj & 2) ? ((jj & 1) ? a3 : a2) : ((jj & 1) ? a1 : a0);
        float hv = ftanh(sum + xuA);
        out[obA + (size_t)s * Hsz] = hv;
        if (s + 1 < Tsz)
          __hip_atomic_store(&atoms[((size_t)pn * Bsz + 2 * g + 0) * Hsz + col],
                             packha(hv, s + 1), __ATOMIC_RELAXED,
                             __HIP_MEMORY_SCOPE_AGENT);
        xuA = xan;
      }
    }
    // ======== phase 2: gather pipe B state s (propagated during phase 1) ====
    if (s > 0) {
      float hv = poll_one(&atoms[((size_t)par * Bsz + 2 * g + 1) * Hsz + pk], s);
      hB[par * 512 + islot] = hv;
    }
    __syncthreads();

    // ======== phase 3: pipe B step s ========
    float xbn = (own && s + 1 < Tsz) ? out[obB + (size_t)(s + 1) * Hsz] : 0.f;
    {
      const float* hq = &hB[par * 512 + hb2];
      float b0 = 0.f, b1 = 0.f, b2 = 0.f, b3 = 0.f;
      PIPE_FMA(hq, b0, b1, b2, b3)
      RED(b0) RED(b1) RED(b2) RED(b3)
      if (own) {
        float sum = (jj & 2) ? ((jj & 1) ? b3 : b2) : ((jj & 1) ? b1 : b0);
        float hv = ftanh(sum + xuB);
        out[obB + (size_t)s * Hsz] = hv;
        if (s + 1 < Tsz)
          __hip_atomic_store(&atoms[((size_t)pn * Bsz + 2 * g + 1) * Hsz + col],
                             packha(hv, s + 1), __ATOMIC_RELAXED,
                             __HIP_MEMORY_SCOPE_AGENT);
        xuB = xbn;
      }
    }
    // ======== phase 4: gather pipe A state s+1 (propagated during 2+3) ======
    if (s + 1 < Tsz) {
      float hv =
          poll_one(&atoms[((size_t)pn * Bsz + 2 * g + 0) * Hsz + pk], s + 1);
      hA[pn * 512 + islot] = hv;
    }
    __syncthreads();
  }
#undef PK2
#undef PIPE_FMA
#undef RED
}

extern "C" void kernel_launch(void* const* d_in, const int* in_sizes, int n_in,
                              void* d_out, int out_size, void* d_ws, size_t ws_size,
                              hipStream_t stream) {
  const float* x  = (const float*)d_in[0];
  const float* h0 = (const float*)d_in[1];
  const float* U  = (const float*)d_in[2];
  const float* V  = (const float*)d_in[3];
  const float* b  = (const float*)d_in[4];
  float* out = (float*)d_out;
  // atoms: [2][Bsz][Hsz] x 8B = 512 KB of d_ws. Tag exact-match vs poison:
  // 0xAAAAAAAA never equals a live tag -> no memset needed.
  unsigned long long* atoms = (unsigned long long*)d_ws;

  static const int kDynLds = (32768 + 2 * 1024) * 4;  // 136 KB
  (void)hipFuncSetAttribute(reinterpret_cast<const void*>(p2_rnn),
                            hipFuncAttributeMaxDynamicSharedMemorySize, kDynLds);

  // Phase 1: out = x @ U + b
  p1_gemm<<<dim3(2048), dim3(256), 0, stream>>>(x, U, b, out);

  // Phase 2: in-place recurrence over T (two batch-pipelines per block)
  p2_rnn<<<dim3(256), dim3(512), kDynLds, stream>>>(h0, V, out, atoms);
}